// Round 2
// baseline (845.254 us; speedup 1.0000x reference)
//
#include <hip/hip_runtime.h>

#define Bn 65536
#define Tn 100
#define Cn 7

__device__ __forceinline__ float fast_rcp(float x) { return __builtin_amdgcn_rcpf(x); }
__device__ __forceinline__ float sig_f(float x) { return fast_rcp(1.f + __expf(-x)); }
// tanh(x) = 1 - 2/(e^{2x}+1): saturates cleanly to +/-1, no inf/inf NaN
__device__ __forceinline__ float tanh_f(float x) { return 1.f - 2.f * fast_rcp(__expf(2.f * x) + 1.f); }

// ---------------- K0: transpose fc1_w (64,400) -> fc1_wt (400,64) ----------------
__global__ void fc1t_kernel(const float* __restrict__ fc1_w, float* __restrict__ fc1_wt) {
    int idx = blockIdx.x * 256 + threadIdx.x;  // 25600 total
    if (idx < 400 * 64) {
        int col = idx >> 6;   // 0..399
        int k = idx & 63;     // 0..63
        fc1_wt[idx] = fc1_w[k * 400 + col];
    }
}

// ---------------- K1: bidirectional LSTM layer 0 ----------------
// 512 blocks x 256: 128 samples/block, tid<128 fwd, tid>=128 rev.
// x staged via register-batched coalesced loads (all 70 loads in flight at once),
// software-pipelined one chunk ahead so HBM latency hides under the 10-step compute.
// h1 written [T][4][B] (planes 0,1 fwd; 2,3 rev) -> coalesced for layer 1.
__global__ __launch_bounds__(256, 2) void l0_kernel(
    const float* __restrict__ x,
    const float* __restrict__ wih_f, const float* __restrict__ whh_f,
    const float* __restrict__ bih_f, const float* __restrict__ bhh_f,
    const float* __restrict__ wih_r, const float* __restrict__ whh_r,
    const float* __restrict__ bih_r, const float* __restrict__ bhh_r,
    float* __restrict__ h1)
{
    __shared__ float xsF[128 * 71];  // stride 71: (7s+off)%32 -> 2-way only (free)
    __shared__ float xsR[128 * 71];

    const int tid = threadIdx.x;
    const int rev = tid >> 7;       // wave-uniform
    const int s   = tid & 127;
    const int b   = blockIdx.x * 128 + s;

    const float* wih = rev ? wih_r : wih_f;
    const float* whh = rev ? whh_r : whh_f;
    const float* bih = rev ? bih_r : bih_f;
    const float* bhh = rev ? bhh_r : bhh_f;

    float wi[56], wh[16], bias[8];
#pragma unroll
    for (int k = 0; k < 56; ++k) wi[k] = wih[k];
#pragma unroll
    for (int k = 0; k < 16; ++k) wh[k] = whh[k];
#pragma unroll
    for (int k = 0; k < 8; ++k) bias[k] = bih[k] + bhh[k];

    // address tables (chunk-invariant): f = tid + 256j -> sample ss, offset r
    int goff[35], loff[35];
#pragma unroll
    for (int j = 0; j < 35; ++j) {
        int f  = tid + 256 * j;
        int ss = f / 70;
        int r  = f - ss * 70;
        goff[j] = ss * 700 + r;   // dword offset from (xblk + t0*7)
        loff[j] = f + ss;         // == ss*71 + r
    }

    const float* xblk = x + (size_t)blockIdx.x * 128 * 700;

    float vF[35], vR[35];
    // prologue: batch-load chunk 0 (all loads issued before any use)
    {
        const float* pF = xblk;            // t0F = 0
        const float* pR = xblk + 90 * 7;   // t0R = 90
#pragma unroll
        for (int j = 0; j < 35; ++j) { vF[j] = pF[goff[j]]; vR[j] = pR[goff[j]]; }
    }

    float h0 = 0.f, h1v = 0.f, c0 = 0.f, c1 = 0.f;
    const float* xs = rev ? xsR : xsF;

#pragma unroll 1
    for (int ch = 0; ch < 10; ++ch) {
        __syncthreads();  // previous chunk's readers done
#pragma unroll
        for (int j = 0; j < 35; ++j) { xsF[loff[j]] = vF[j]; xsR[loff[j]] = vR[j]; }
        __syncthreads();

        // prefetch next chunk into registers (hidden under compute below)
        {
            const int cn = (ch < 9) ? ch + 1 : 9;
            const float* pF = xblk + cn * 70;          // (cn*10)*7
            const float* pR = xblk + (90 - cn * 10) * 7;
#pragma unroll
            for (int j = 0; j < 35; ++j) { vF[j] = pF[goff[j]]; vR[j] = pR[goff[j]]; }
        }

        const int t0 = rev ? (90 - ch * 10) : (ch * 10);
        for (int tt = 0; tt < 10; ++tt) {
            const int rr = rev ? (9 - tt) : tt;
            const int t  = t0 + rr;
            const float* xrow = xs + s * 71 + rr * 7;

            float g[8];
#pragma unroll
            for (int k = 0; k < 8; ++k) g[k] = bias[k];
#pragma unroll
            for (int c = 0; c < 7; ++c) {
                const float xv = xrow[c];
#pragma unroll
                for (int k = 0; k < 8; ++k) g[k] = fmaf(wi[k * 7 + c], xv, g[k]);
            }
#pragma unroll
            for (int k = 0; k < 8; ++k)
                g[k] = fmaf(wh[k * 2], h0, fmaf(wh[k * 2 + 1], h1v, g[k]));

            const float i0 = sig_f(g[0]), i1 = sig_f(g[1]);
            const float f0 = sig_f(g[2]), f1 = sig_f(g[3]);
            const float q0 = tanh_f(g[4]), q1 = tanh_f(g[5]);
            const float o0 = sig_f(g[6]), o1 = sig_f(g[7]);
            c0 = fmaf(f0, c0, i0 * q0);
            c1 = fmaf(f1, c1, i1 * q1);
            h0  = o0 * tanh_f(c0);
            h1v = o1 * tanh_f(c1);

            const size_t ob = ((size_t)t * 4 + rev * 2) * Bn + b;
            h1[ob]      = h0;
            h1[ob + Bn] = h1v;
        }
    }
}

// ---------------- K2: bidirectional LSTM layer 1 + fused ReLU/fc1/ReLU/fc2 ----------------
// fc1 weights staged per-25-step slab in LDS (kills serialized scalar-cache round trips);
// slab loads register-batched one chunk ahead. h1 prefetched 2 steps deep.
__global__ __launch_bounds__(256, 2) void l1fc_kernel(
    const float* __restrict__ h1,
    const float* __restrict__ wih_f, const float* __restrict__ whh_f,
    const float* __restrict__ bih_f, const float* __restrict__ bhh_f,
    const float* __restrict__ wih_r, const float* __restrict__ whh_r,
    const float* __restrict__ bih_r, const float* __restrict__ bhh_r,
    const float* __restrict__ fc1_wt,   // [400][64]
    const float* __restrict__ fc1_b,
    const float* __restrict__ fc2_w,    // [20][64]
    const float* __restrict__ fc2_b,
    float* __restrict__ out)            // [B][20]
{
    __shared__ float smem[128 * 65];    // [0,6400): weight slab; later reused as xch[128][65]

    const int tid = threadIdx.x;
    const int rev = tid >> 7;
    const int s   = tid & 127;
    const int b   = blockIdx.x * 128 + s;

    const float* wih = rev ? wih_r : wih_f;
    const float* whh = rev ? whh_r : whh_f;
    const float* bih = rev ? bih_r : bih_f;
    const float* bhh = rev ? bhh_r : bhh_f;

    float wi[32], wh[16], bias[8];
#pragma unroll
    for (int k = 0; k < 32; ++k) wi[k] = wih[k];
#pragma unroll
    for (int k = 0; k < 16; ++k) wh[k] = whh[k];
#pragma unroll
    for (int k = 0; k < 8; ++k) bias[k] = bih[k] + bhh[k];

    float acc[64];
#pragma unroll
    for (int k = 0; k < 64; ++k) acc[k] = 0.f;

    // weight slab gather: element e -> fwd slab rows (4t,4t+1), rev slab rows (4t+2,4t+3)
    float wreg[25];
    auto load_wchunk = [&](int s0) {
#pragma unroll
        for (int j = 0; j < 25; ++j) {
            int e    = tid + 256 * j;
            int k    = e & 63;
            int rr   = e >> 6;          // 0..99
            int half = (rr >= 50) ? 1 : 0;
            int q    = half ? rr - 50 : rr;
            int jj   = q >> 1;
            int c    = q & 1;
            int t    = half ? (99 - (s0 + jj)) : (s0 + jj);
            int row  = t * 4 + half * 2 + c;
            wreg[j]  = fc1_wt[row * 64 + k];
        }
    };
    load_wchunk(0);

    const float* hb = h1 + b;
    float h0 = 0.f, h1v = 0.f, c0 = 0.f, c1 = 0.f;

    // 2-deep h1 pipeline
    float a0, a1, a2, a3, p0, p1, p2, p3;
    {
        const size_t i0o = (size_t)(rev ? 99 : 0) * 4 * Bn;
        a0 = hb[i0o]; a1 = hb[i0o + Bn]; a2 = hb[i0o + 2 * Bn]; a3 = hb[i0o + 3 * Bn];
        const size_t i1o = (size_t)(rev ? 98 : 1) * 4 * Bn;
        p0 = hb[i1o]; p1 = hb[i1o + Bn]; p2 = hb[i1o + 2 * Bn]; p3 = hb[i1o + 3 * Bn];
    }

#pragma unroll 1
    for (int cc = 0; cc < 4; ++cc) {
        __syncthreads();                 // previous slab's readers done
#pragma unroll
        for (int j = 0; j < 25; ++j) smem[tid + 256 * j] = wreg[j];
        __syncthreads();
        if (cc < 3) load_wchunk(25 * (cc + 1));   // hidden under the 25-step compute

        const float* wb = smem + (rev ? 3200 : 0);

#pragma unroll 1
        for (int jl = 0; jl < 25; ++jl) {
            const int step = cc * 25 + jl;
            // prefetch step+2
            const int sp = (step + 2 <= 99) ? step + 2 : 99;
            const size_t nb = (size_t)(rev ? 99 - sp : sp) * 4 * Bn;
            const float n0 = hb[nb], n1 = hb[nb + Bn], n2 = hb[nb + 2 * Bn], n3 = hb[nb + 3 * Bn];

            float g[8];
#pragma unroll
            for (int k = 0; k < 8; ++k) {
                g[k] = bias[k];
                g[k] = fmaf(wi[k * 4 + 0], a0, g[k]);
                g[k] = fmaf(wi[k * 4 + 1], a1, g[k]);
                g[k] = fmaf(wi[k * 4 + 2], a2, g[k]);
                g[k] = fmaf(wi[k * 4 + 3], a3, g[k]);
                g[k] = fmaf(wh[k * 2], h0, fmaf(wh[k * 2 + 1], h1v, g[k]));
            }
            const float i0 = sig_f(g[0]), i1 = sig_f(g[1]);
            const float f0 = sig_f(g[2]), f1 = sig_f(g[3]);
            const float q0 = tanh_f(g[4]), q1 = tanh_f(g[5]);
            const float o0 = sig_f(g[6]), o1 = sig_f(g[7]);
            c0 = fmaf(f0, c0, i0 * q0);
            c1 = fmaf(f1, c1, i1 * q1);
            h0  = o0 * tanh_f(c0);
            h1v = o1 * tanh_f(c1);

            const float v0 = fmaxf(h0, 0.f);
            const float v1 = fmaxf(h1v, 0.f);
            const float* wc = wb + jl * 128;   // uniform -> LDS broadcast, conflict-free
#pragma unroll
            for (int k = 0; k < 64; ++k)
                acc[k] = fmaf(wc[k], v0, fmaf(wc[64 + k], v1, acc[k]));

            a0 = p0; a1 = p1; a2 = p2; a3 = p3;
            p0 = n0; p1 = n1; p2 = n2; p3 = n3;
        }
    }

    __syncthreads();   // last slab's readers done before aliasing smem as xch
    if (rev) {
#pragma unroll
        for (int k = 0; k < 64; ++k) smem[s * 65 + k] = acc[k];
    }
    __syncthreads();

    float y[20];
    if (!rev) {
        float z[64];
#pragma unroll
        for (int k = 0; k < 64; ++k)
            z[k] = fmaxf(acc[k] + smem[s * 65 + k] + fc1_b[k], 0.f);
#pragma unroll
        for (int o = 0; o < 20; ++o) {
            float r = fc2_b[o];
#pragma unroll
            for (int k = 0; k < 64; ++k) r = fmaf(fc2_w[o * 64 + k], z[k], r);
            y[o] = r;
        }
    }
    __syncthreads();
    if (!rev) {
#pragma unroll
        for (int o = 0; o < 20; ++o) smem[s * 20 + o] = y[o];
    }
    __syncthreads();
    for (int f = tid; f < 128 * 20; f += 256)
        out[(size_t)blockIdx.x * (128 * 20) + f] = smem[f];
}

extern "C" void kernel_launch(void* const* d_in, const int* in_sizes, int n_in,
                              void* d_out, int out_size, void* d_ws, size_t ws_size,
                              hipStream_t stream) {
    const float* x = (const float*)d_in[0];
    const float* w_ih_l0  = (const float*)d_in[1];
    const float* w_hh_l0  = (const float*)d_in[2];
    const float* b_ih_l0  = (const float*)d_in[3];
    const float* b_hh_l0  = (const float*)d_in[4];
    const float* w_ih_l0r = (const float*)d_in[5];
    const float* w_hh_l0r = (const float*)d_in[6];
    const float* b_ih_l0r = (const float*)d_in[7];
    const float* b_hh_l0r = (const float*)d_in[8];
    const float* w_ih_l1  = (const float*)d_in[9];
    const float* w_hh_l1  = (const float*)d_in[10];
    const float* b_ih_l1  = (const float*)d_in[11];
    const float* b_hh_l1  = (const float*)d_in[12];
    const float* w_ih_l1r = (const float*)d_in[13];
    const float* w_hh_l1r = (const float*)d_in[14];
    const float* b_ih_l1r = (const float*)d_in[15];
    const float* b_hh_l1r = (const float*)d_in[16];
    const float* fc1_w = (const float*)d_in[17];
    const float* fc1_b = (const float*)d_in[18];
    const float* fc2_w = (const float*)d_in[19];
    const float* fc2_b = (const float*)d_in[20];

    float* h1     = (float*)d_ws;                                  // [100][4][65536] f32
    float* fc1_wt = (float*)((char*)d_ws + (size_t)Tn * 4 * Bn * sizeof(float));  // [400][64]

    fc1t_kernel<<<100, 256, 0, stream>>>(fc1_w, fc1_wt);
    l0_kernel<<<512, 256, 0, stream>>>(x,
        w_ih_l0, w_hh_l0, b_ih_l0, b_hh_l0,
        w_ih_l0r, w_hh_l0r, b_ih_l0r, b_hh_l0r, h1);
    l1fc_kernel<<<512, 256, 0, stream>>>(h1,
        w_ih_l1, w_hh_l1, b_ih_l1, b_hh_l1,
        w_ih_l1r, w_hh_l1r, b_ih_l1r, b_hh_l1r,
        fc1_wt, fc1_b, fc2_w, fc2_b, (float*)d_out);
}

// Round 3
// 466.353 us; speedup vs baseline: 1.8125x; 1.8125x over previous
//
#include <hip/hip_runtime.h>

#define Bn 65536
#define Tn 100
#define Cn 7

__device__ __forceinline__ float fast_rcp(float x) { return __builtin_amdgcn_rcpf(x); }
__device__ __forceinline__ float sig_f(float x) { return fast_rcp(1.f + __expf(-x)); }
// tanh(x) = 1 - 2/(e^{2x}+1): saturates cleanly to +/-1, no inf/inf NaN
__device__ __forceinline__ float tanh_f(float x) { return 1.f - 2.f * fast_rcp(__expf(2.f * x) + 1.f); }

typedef const __attribute__((address_space(1))) void* gp_t;
typedef __attribute__((address_space(3))) void* sp_t;
// async global->LDS dword copy: each active lane loads 4B from its own gptr;
// LDS dest = first-active-lane base + laneId*4 (so pass per-lane l = base+lane too).
__device__ __forceinline__ void async_copy_dw(const float* g, float* l) {
    __builtin_amdgcn_global_load_lds((gp_t)g, (sp_t)l, 4, 0, 0);
}

// ---------------- K0: transpose fc1_w (64,400) -> fc1_wt (400,64) ----------------
__global__ void fc1t_kernel(const float* __restrict__ fc1_w, float* __restrict__ fc1_wt) {
    int idx = blockIdx.x * 256 + threadIdx.x;  // 25600 total
    if (idx < 400 * 64) {
        int col = idx >> 6;   // 0..399
        int k = idx & 63;     // 0..63
        fc1_wt[idx] = fc1_w[k * 400 + col];
    }
}

// ---------------- K1: bidirectional LSTM layer 0 ----------------
// 512 blocks x 256: 128 samples/block, tid<128 fwd, tid>=128 rev.
// x staged per 10-step chunk via async global_load_lds (no VGPR round trip, no spill),
// rows at stride 71 -> conflict-free compute reads. Single-buffered: one barrier
// drain (~700cy) per chunk is the only exposed latency.
// h1 written [T][4][B] (planes 0,1 fwd; 2,3 rev) -> coalesced for layer 1.
__global__ __launch_bounds__(256) void l0_kernel(
    const float* __restrict__ x,
    const float* __restrict__ wih_f, const float* __restrict__ whh_f,
    const float* __restrict__ bih_f, const float* __restrict__ bhh_f,
    const float* __restrict__ wih_r, const float* __restrict__ whh_r,
    const float* __restrict__ bih_r, const float* __restrict__ bhh_r,
    float* __restrict__ h1)
{
    __shared__ float xsF[128 * 71];  // row stride 71: bank = (7s+off)%32, 2-way only (free)
    __shared__ float xsR[128 * 71];

    const int tid  = threadIdx.x;
    const int rev  = tid >> 7;       // wave-uniform (waves 0,1 fwd; 2,3 rev)
    const int s    = tid & 127;
    const int b    = blockIdx.x * 128 + s;
    const int wv   = tid >> 6;       // wave id 0..3 (stages rows wv*32..+31)
    const int lane = tid & 63;

    const float* wih = rev ? wih_r : wih_f;
    const float* whh = rev ? whh_r : whh_f;
    const float* bih = rev ? bih_r : bih_f;
    const float* bhh = rev ? bhh_r : bhh_f;

    float wi[56], wh[16], bias[8];
#pragma unroll
    for (int k = 0; k < 56; ++k) wi[k] = wih[k];
#pragma unroll
    for (int k = 0; k < 16; ++k) wh[k] = whh[k];
#pragma unroll
    for (int k = 0; k < 8; ++k) bias[k] = bih[k] + bhh[k];

    float h0 = 0.f, h1v = 0.f, c0 = 0.f, c1 = 0.f;
    const float* xs = rev ? xsR : xsF;

#pragma unroll 1
    for (int ch = 0; ch < 10; ++ch) {
        __syncthreads();  // previous chunk's readers done
        {
            const float* srcF = x + (size_t)(blockIdx.x * 128 + wv * 32) * 700 + ch * 70;
            const float* srcR = x + (size_t)(blockIdx.x * 128 + wv * 32) * 700 + (630 - ch * 70);
            float* dF = xsF + (wv * 32) * 71;
            float* dR = xsR + (wv * 32) * 71;
#pragma unroll 1
            for (int i = 0; i < 32; ++i) {
                async_copy_dw(srcF + lane, dF + lane);           // floats [0,64)
                async_copy_dw(srcR + lane, dR + lane);
                if (lane < 6) {                                  // exact tail [64,70), no OOB
                    async_copy_dw(srcF + 64 + lane, dF + 64 + lane);
                    async_copy_dw(srcR + 64 + lane, dR + 64 + lane);
                }
                srcF += 700; srcR += 700; dF += 71; dR += 71;
            }
        }
        __builtin_amdgcn_s_waitcnt(0);   // drain async copies
        __syncthreads();

        const int t0 = rev ? (90 - ch * 10) : (ch * 10);
#pragma unroll 1
        for (int tt = 0; tt < 10; ++tt) {
            const int rr = rev ? (9 - tt) : tt;
            const int t  = t0 + rr;
            const float* xrow = xs + s * 71 + rr * 7;

            float g[8];
#pragma unroll
            for (int k = 0; k < 8; ++k) g[k] = bias[k];
#pragma unroll
            for (int c = 0; c < 7; ++c) {
                const float xv = xrow[c];
#pragma unroll
                for (int k = 0; k < 8; ++k) g[k] = fmaf(wi[k * 7 + c], xv, g[k]);
            }
#pragma unroll
            for (int k = 0; k < 8; ++k)
                g[k] = fmaf(wh[k * 2], h0, fmaf(wh[k * 2 + 1], h1v, g[k]));

            const float i0 = sig_f(g[0]), i1 = sig_f(g[1]);
            const float f0 = sig_f(g[2]), f1 = sig_f(g[3]);
            const float q0 = tanh_f(g[4]), q1 = tanh_f(g[5]);
            const float o0 = sig_f(g[6]), o1 = sig_f(g[7]);
            c0 = fmaf(f0, c0, i0 * q0);
            c1 = fmaf(f1, c1, i1 * q1);
            h0  = o0 * tanh_f(c0);
            h1v = o1 * tanh_f(c1);

            const size_t ob = ((size_t)t * 4 + rev * 2) * Bn + b;
            h1[ob]      = h0;
            h1[ob + Bn] = h1v;
        }
    }
}

// ---------------- K2: bidirectional LSTM layer 1 + fused ReLU/fc1/ReLU/fc2 ----------------
// fc1 weights staged per-25-step slab via async global_load_lds (identity copy, no gather
// math, no registers): fwd slab rows [100cc,+100), rev slab rows [300-100cc,+100).
// Per-step weight reads are uniform ds_read_b128 broadcasts. h1 in a depth-3 register pipe.
__global__ __launch_bounds__(256) void l1fc_kernel(
    const float* __restrict__ h1,
    const float* __restrict__ wih_f, const float* __restrict__ whh_f,
    const float* __restrict__ bih_f, const float* __restrict__ bhh_f,
    const float* __restrict__ wih_r, const float* __restrict__ whh_r,
    const float* __restrict__ bih_r, const float* __restrict__ bhh_r,
    const float* __restrict__ fc1_wt,   // [400][64]
    const float* __restrict__ fc1_b,
    const float* __restrict__ fc2_w,    // [20][64]
    const float* __restrict__ fc2_b,
    float* __restrict__ out)            // [B][20]
{
    __shared__ float lds_w[12800];      // [0,6400) fwd slab, [6400,12800) rev slab; reused for epilogue

    const int tid = threadIdx.x;
    const int rev = tid >> 7;
    const int s   = tid & 127;
    const int b   = blockIdx.x * 128 + s;

    const float* wih = rev ? wih_r : wih_f;
    const float* whh = rev ? whh_r : whh_f;
    const float* bih = rev ? bih_r : bih_f;
    const float* bhh = rev ? bhh_r : bhh_f;

    float wi[32], wh[16], bias[8];
#pragma unroll
    for (int k = 0; k < 32; ++k) wi[k] = wih[k];
#pragma unroll
    for (int k = 0; k < 16; ++k) wh[k] = whh[k];
#pragma unroll
    for (int k = 0; k < 8; ++k) bias[k] = bih[k] + bhh[k];

    float acc[64];
#pragma unroll
    for (int k = 0; k < 64; ++k) acc[k] = 0.f;

    const float* hb = h1 + b;
    float h0 = 0.f, h1v = 0.f, c0 = 0.f, c1 = 0.f;

    // depth-3 h1 register pipeline
    float a0, a1, a2, a3, p10, p11, p12, p13, p20, p21, p22, p23;
    {
        size_t o0 = (size_t)(rev ? 99 : 0) * 4 * Bn;
        a0 = hb[o0]; a1 = hb[o0 + Bn]; a2 = hb[o0 + 2 * Bn]; a3 = hb[o0 + 3 * Bn];
        size_t o1 = (size_t)(rev ? 98 : 1) * 4 * Bn;
        p10 = hb[o1]; p11 = hb[o1 + Bn]; p12 = hb[o1 + 2 * Bn]; p13 = hb[o1 + 3 * Bn];
        size_t o2 = (size_t)(rev ? 97 : 2) * 4 * Bn;
        p20 = hb[o2]; p21 = hb[o2 + Bn]; p22 = hb[o2 + 2 * Bn]; p23 = hb[o2 + 3 * Bn];
    }

#pragma unroll 1
    for (int cc = 0; cc < 4; ++cc) {
        __syncthreads();                 // previous slab's readers done
        {
            const float* bf = fc1_wt + 6400 * cc;          // rows [100cc, +100)
            const float* br = fc1_wt + 19200 - 6400 * cc;  // rows [300-100cc, +100)
#pragma unroll 1
            for (int j = 0; j < 25; ++j) {
                async_copy_dw(bf + j * 256 + tid, lds_w + j * 256 + tid);
                async_copy_dw(br + j * 256 + tid, lds_w + 6400 + j * 256 + tid);
            }
        }
        __builtin_amdgcn_s_waitcnt(0);
        __syncthreads();

#pragma unroll 1
        for (int jl = 0; jl < 25; ++jl) {
            const int step = cc * 25 + jl;
            // prefetch step+3
            const int sp = (step + 3 <= 99) ? step + 3 : 99;
            const size_t nb = (size_t)(rev ? 99 - sp : sp) * 4 * Bn;
            const float n0 = hb[nb], n1 = hb[nb + Bn], n2 = hb[nb + 2 * Bn], n3 = hb[nb + 3 * Bn];

            float g[8];
#pragma unroll
            for (int k = 0; k < 8; ++k) {
                g[k] = bias[k];
                g[k] = fmaf(wi[k * 4 + 0], a0, g[k]);
                g[k] = fmaf(wi[k * 4 + 1], a1, g[k]);
                g[k] = fmaf(wi[k * 4 + 2], a2, g[k]);
                g[k] = fmaf(wi[k * 4 + 3], a3, g[k]);
                g[k] = fmaf(wh[k * 2], h0, fmaf(wh[k * 2 + 1], h1v, g[k]));
            }
            const float i0 = sig_f(g[0]), i1 = sig_f(g[1]);
            const float f0 = sig_f(g[2]), f1 = sig_f(g[3]);
            const float q0 = tanh_f(g[4]), q1 = tanh_f(g[5]);
            const float o0 = sig_f(g[6]), o1 = sig_f(g[7]);
            c0 = fmaf(f0, c0, i0 * q0);
            c1 = fmaf(f1, c1, i1 * q1);
            h0  = o0 * tanh_f(c0);
            h1v = o1 * tanh_f(c1);

            const float v0 = fmaxf(h0, 0.f);
            const float v1 = fmaxf(h1v, 0.f);
            // fwd: rows 4t,4t+1 at slab offset 256*jl; rev: rows 4t+2,4t+3 at 12672-256*jl
            const float4* w4 = (const float4*)(lds_w + (rev ? (12672 - 256 * jl) : (256 * jl)));
#pragma unroll
            for (int q = 0; q < 16; ++q) {
                const float4 wa = w4[q];        // first row (v0)
                const float4 wb = w4[q + 16];   // second row (v1)
                acc[4 * q + 0] = fmaf(wa.x, v0, fmaf(wb.x, v1, acc[4 * q + 0]));
                acc[4 * q + 1] = fmaf(wa.y, v0, fmaf(wb.y, v1, acc[4 * q + 1]));
                acc[4 * q + 2] = fmaf(wa.z, v0, fmaf(wb.z, v1, acc[4 * q + 2]));
                acc[4 * q + 3] = fmaf(wa.w, v0, fmaf(wb.w, v1, acc[4 * q + 3]));
            }

            a0 = p10; a1 = p11; a2 = p12; a3 = p13;
            p10 = p20; p11 = p21; p12 = p22; p13 = p23;
            p20 = n0; p21 = n1; p22 = n2; p23 = n3;
        }
    }

    __syncthreads();   // last slab's readers done before reusing lds_w
    if (rev) {
#pragma unroll
        for (int k = 0; k < 64; ++k) lds_w[s * 65 + k] = acc[k];
    }
    __syncthreads();

    float y[20];
    if (!rev) {
        float z[64];
#pragma unroll
        for (int k = 0; k < 64; ++k)
            z[k] = fmaxf(acc[k] + lds_w[s * 65 + k] + fc1_b[k], 0.f);
#pragma unroll
        for (int o = 0; o < 20; ++o) {
            float r = fc2_b[o];
#pragma unroll
            for (int k = 0; k < 64; ++k) r = fmaf(fc2_w[o * 64 + k], z[k], r);
            y[o] = r;
        }
    }
    __syncthreads();
    if (!rev) {
#pragma unroll
        for (int o = 0; o < 20; ++o) lds_w[s * 20 + o] = y[o];
    }
    __syncthreads();
    for (int f = tid; f < 128 * 20; f += 256)
        out[(size_t)blockIdx.x * (128 * 20) + f] = lds_w[f];
}

extern "C" void kernel_launch(void* const* d_in, const int* in_sizes, int n_in,
                              void* d_out, int out_size, void* d_ws, size_t ws_size,
                              hipStream_t stream) {
    const float* x = (const float*)d_in[0];
    const float* w_ih_l0  = (const float*)d_in[1];
    const float* w_hh_l0  = (const float*)d_in[2];
    const float* b_ih_l0  = (const float*)d_in[3];
    const float* b_hh_l0  = (const float*)d_in[4];
    const float* w_ih_l0r = (const float*)d_in[5];
    const float* w_hh_l0r = (const float*)d_in[6];
    const float* b_ih_l0r = (const float*)d_in[7];
    const float* b_hh_l0r = (const float*)d_in[8];
    const float* w_ih_l1  = (const float*)d_in[9];
    const float* w_hh_l1  = (const float*)d_in[10];
    const float* b_ih_l1  = (const float*)d_in[11];
    const float* b_hh_l1  = (const float*)d_in[12];
    const float* w_ih_l1r = (const float*)d_in[13];
    const float* w_hh_l1r = (const float*)d_in[14];
    const float* b_ih_l1r = (const float*)d_in[15];
    const float* b_hh_l1r = (const float*)d_in[16];
    const float* fc1_w = (const float*)d_in[17];
    const float* fc1_b = (const float*)d_in[18];
    const float* fc2_w = (const float*)d_in[19];
    const float* fc2_b = (const float*)d_in[20];

    float* h1     = (float*)d_ws;                                  // [100][4][65536] f32
    float* fc1_wt = (float*)((char*)d_ws + (size_t)Tn * 4 * Bn * sizeof(float));  // [400][64]

    fc1t_kernel<<<100, 256, 0, stream>>>(fc1_w, fc1_wt);
    l0_kernel<<<512, 256, 0, stream>>>(x,
        w_ih_l0, w_hh_l0, b_ih_l0, b_hh_l0,
        w_ih_l0r, w_hh_l0r, b_ih_l0r, b_hh_l0r, h1);
    l1fc_kernel<<<512, 256, 0, stream>>>(h1,
        w_ih_l1, w_hh_l1, b_ih_l1, b_hh_l1,
        w_ih_l1r, w_hh_l1r, b_ih_l1r, b_hh_l1r,
        fc1_wt, fc1_b, fc2_w, fc2_b, (float*)d_out);
}